// Round 7
// baseline (119.526 us; speedup 1.0000x reference)
//
#include <hip/hip_runtime.h>
#include <hip/hip_bf16.h>

#define TEMP_INV 14.285714285714286f     // 1/0.07
#define KL2E     20.60992947626f         // TEMP_INV * log2(e)
#define NC2      (-20.60992947626f)      // shift: exp((dot-1)/T) as exp2(dot*KL2E + NC2)
#define NROWS 2048
#define DDIM 128

typedef __attribute__((ext_vector_type(8))) short bf16x8;
typedef __attribute__((ext_vector_type(4))) float f32x4;

// async global->LDS, 16B/lane; LDS dest = wave-uniform base + lane*16
#define GLOAD16(g, l) \
  __builtin_amdgcn_global_load_lds((const __attribute__((address_space(1))) void*)(g), \
                                   (__attribute__((address_space(3))) void*)(l), 16, 0, 0)

// ---------------- K1: cast fp32 [16,1024,2,128] -> bf16 contrast [16,2048,128]
__global__ __launch_bounds__(256) void cast_reorder_kernel(
    const float* __restrict__ feat, __hip_bfloat16* __restrict__ out)
{
    int t = blockIdx.x * blockDim.x + threadIdx.x;
    int e = t << 2;
    int d = e & 127;
    int v = (e >> 7) & 1;
    int i = (e >> 8) & 1023;
    int b = e >> 18;
    const float4 f = *reinterpret_cast<const float4*>(feat + e);
    union { __hip_bfloat16 h[4]; uint2 u; } o;
    o.h[0] = __float2bfloat16(f.x);
    o.h[1] = __float2bfloat16(f.y);
    o.h[2] = __float2bfloat16(f.z);
    o.h[3] = __float2bfloat16(f.w);
    size_t oe = (size_t)(((b << 11) + (v << 10) + i)) * DDIM + d;
    *reinterpret_cast<uint2*>(out + oe) = o.u;
}

// ---------------- K2: barrier-free per-wave Gram pipeline
// grid 1024 = 16 batches x 32 row-blocks(64) x 2 col-halves(1024).
// 256 thr = 4 waves; wave w owns rows n0+w*16 .. +15, streams 64 col-steps of 16.
__global__ __launch_bounds__(256, 4) void supcon_main_kernel(
    const __hip_bfloat16* __restrict__ contrast,
    const int* __restrict__ labels,
    float* __restrict__ rsum_ws, float* __restrict__ ps_ws, float* __restrict__ sd_ws)
{
    __shared__ __align__(16) char wbuf[4][2][4096];   // per-wave private dbuf (32 KB)
    __shared__ int slab[1024];                        // labels (4 KB)

    const int tid  = threadIdx.x;
    const int lane = tid & 63;
    const int w    = tid >> 6;
    const int hi   = lane >> 4;       // 0..3
    const int lo   = lane & 15;       // 0..15

    // XCD-aware decode: each XCD owns 2 whole batches (panels L2-resident)
    const int bid = blockIdx.x;
    const int xcd = bid & 7, idx = bid >> 3;          // idx 0..127
    const int b   = xcd * 2 + (idx >> 6);
    const int rem = idx & 63;
    const int rb  = rem >> 1, ch = rem & 1;
    const int n0  = rb * 64;          // block row base
    const int wr0 = n0 + w * 16;      // wave row base
    const int cb0 = ch * 1024;        // col base

    const __hip_bfloat16* cbase = contrast + (size_t)b * NROWS * DDIM;
    const int* lb = labels + b * 1024;

    // stage labels (each wave loads 256; barrier below publishes)
    #pragma unroll
    for (int it = 0; it < 4; ++it) slab[it * 256 + tid] = lb[it * 256 + tid];

    char* buf0 = &wbuf[w][0][0];

    // ---- stage A rows wr0..wr0+15 into buf0 (swizzled source, linear dest)
    #pragma unroll
    for (int i = 0; i < 4; ++i) {
        const int r = 4 * i + hi;                     // in-tile row 0..15
        GLOAD16(cbase + (size_t)(wr0 + r) * DDIM + ((lo ^ (r & 7)) << 3),
                buf0 + i * 1024);
    }
    asm volatile("s_waitcnt vmcnt(0)" ::: "memory");
    __builtin_amdgcn_sched_barrier(0);

    // afrag: lane reads row lo, chunk q=hi+4ks at swizzled slot (q ^ (lo&7))
    bf16x8 afrag[4];
    int boff[4];
    #pragma unroll
    for (int ks = 0; ks < 4; ++ks) {
        boff[ks] = lo * 256 + (((hi + 4 * ks) ^ (lo & 7)) << 4);
        afrag[ks] = *reinterpret_cast<const bf16x8*>(buf0 + boff[ks]);
    }
    __syncthreads();   // slab visible to all waves (only barrier in the kernel)

    // per-lane row ids / labels (acc lane layout: col=lo, rows hi*4+j)
    int nrow[4], rlab[4];
    #pragma unroll
    for (int j = 0; j < 4; ++j) {
        nrow[j] = wr0 + hi * 4 + j;
        rlab[j] = slab[nrow[j] & 1023];
    }

    // B staging source pointers (per staging-inst i): row s*16 + 4i+hi, swizzled chunk
    const __hip_bfloat16* gsrc[4];
    #pragma unroll
    for (int i = 0; i < 4; ++i) {
        const int r = 4 * i + hi;
        gsrc[i] = cbase + (size_t)(cb0 + r) * DDIM + ((lo ^ (r & 7)) << 3);
    }
    // prologue: stage s=0 into buf0, s=1 into buf1; advance to s=2
    #pragma unroll
    for (int i = 0; i < 4; ++i) GLOAD16(gsrc[i], buf0 + i * 1024);
    #pragma unroll
    for (int i = 0; i < 4; ++i) GLOAD16(gsrc[i] + 16 * DDIM, buf0 + 4096 + i * 1024);
    #pragma unroll
    for (int i = 0; i < 4; ++i) gsrc[i] += 32 * DDIM;

    float se[4] = {0, 0, 0, 0}, ps[4] = {0, 0, 0, 0}, sdg[4] = {0, 0, 0, 0};
    const int sd_step = (wr0 - cb0) >> 4;   // matches s in [0,64) iff diag in this half

    for (int s = 0; s < 64; ++s) {
        char* cur = buf0 + ((s & 1) << 12);
        // wait for buf[s&1]'s 4 loads (the 4 newer, for s+1, stay in flight)
        asm volatile("s_waitcnt vmcnt(4)" ::: "memory");
        __builtin_amdgcn_sched_barrier(0);

        bf16x8 bf[4];
        #pragma unroll
        for (int ks = 0; ks < 4; ++ks)
            bf[ks] = *reinterpret_cast<const bf16x8*>(cur + boff[ks]);

        f32x4 acc = {0.f, 0.f, 0.f, 0.f};
        #pragma unroll
        for (int ks = 0; ks < 4; ++ks)
            acc = __builtin_amdgcn_mfma_f32_16x16x32_bf16(afrag[ks], bf[ks], acc, 0, 0, 0);

        // restage this buffer for step s+2 (wrapped; wrap tiles never get consumed)
        #pragma unroll
        for (int i = 0; i < 4; ++i) { GLOAD16(gsrc[i], cur + i * 1024); gsrc[i] += 16 * DDIM; }
        if (s == 61) {
            #pragma unroll
            for (int i = 0; i < 4; ++i) gsrc[i] -= 64 * 16 * DDIM;   // wrap to s2=0 rows
        }

        // epilogue: col m = cb0 + s*16 + lo  (m & 1023 == s*16 + lo for both halves)
        const int lm = slab[s * 16 + lo];
        #pragma unroll
        for (int j = 0; j < 4; ++j) {
            const float v = acc[j];
            se[j] += exp2f(fmaf(v, KL2E, NC2));
            ps[j] += (lm == rlab[j]) ? v : 0.f;
        }
        if (s == sd_step) {           // uniform branch: one step per wave holds the diag
            const int m = cb0 + s * 16 + lo;
            #pragma unroll
            for (int j = 0; j < 4; ++j)
                if (m == nrow[j]) sdg[j] = acc[j];
        }
    }

    // per-wave reduce over the 16 col-lanes of each quarter, then global atomics
    #pragma unroll
    for (int j = 0; j < 4; ++j) {
        float s = se[j], P = ps[j], D = sdg[j];
        #pragma unroll
        for (int o = 1; o < 16; o <<= 1) {
            s += __shfl_xor(s, o);
            P += __shfl_xor(P, o);
            D += __shfl_xor(D, o);
        }
        if (lo == 0) {
            const int gn = b * NROWS + nrow[j];
            atomicAdd(&rsum_ws[gn], s);
            atomicAdd(&ps_ws[gn], P);
            atomicAdd(&sd_ws[gn], D);
        }
    }
}

// ---------------- K3: finalize — per-row loss from (rsum, ps, sd) + label histogram
__global__ __launch_bounds__(256) void finalize_kernel(
    const int* __restrict__ labels,
    const float* __restrict__ rsum_ws, const float* __restrict__ ps_ws,
    const float* __restrict__ sd_ws, float* __restrict__ out)
{
    __shared__ int cnt_s[64];
    __shared__ float wred[4];
    const int tid = threadIdx.x, lane = tid & 63, wv = tid >> 6;
    const int gid = blockIdx.x * 256 + tid;      // 0..32767 (128 blocks)
    const int b = gid >> 11, n = gid & 2047;
    const int* lb = labels + b * 1024;

    if (tid < 64) cnt_s[tid] = 0;
    __syncthreads();
    #pragma unroll
    for (int k = 0; k < 4; ++k) atomicAdd(&cnt_s[lb[tid * 4 + k]], 1);
    __syncthreads();

    const int l = lb[n & 1023];
    const float poscnt = (float)(2 * cnt_s[l] - 1);   // >=1
    const float D  = sd_ws[gid];                       // exact MFMA self-dot
    const float P  = ps_ws[gid] - D;                   // exclude diagonal
    const float rs = rsum_ws[gid] - exp2f(fmaf(D, KL2E, NC2));
    float mlpp = P * TEMP_INV / poscnt - TEMP_INV - __logf(rs);

    #pragma unroll
    for (int o = 1; o < 64; o <<= 1) mlpp += __shfl_xor(mlpp, o);
    if (lane == 0) wred[wv] = mlpp;
    __syncthreads();
    if (tid == 0)
        atomicAdd(out, -(wred[0] + wred[1] + wred[2] + wred[3]) * (1.0f / 32768.0f));
}

extern "C" void kernel_launch(void* const* d_in, const int* in_sizes, int n_in,
                              void* d_out, int out_size, void* d_ws, size_t ws_size,
                              hipStream_t stream) {
    const float* feat = (const float*)d_in[0];
    const int* labels = (const int*)d_in[1];
    float* out = (float*)d_out;

    char* ws = (char*)d_ws;
    __hip_bfloat16* contrast = (__hip_bfloat16*)ws;            // 8,388,608 B
    float* rsum_ws = (float*)(ws + 8388608);                   // 131,072 B
    float* ps_ws   = (float*)(ws + 8519680);                   // 131,072 B
    float* sd_ws   = (float*)(ws + 8650752);                   // 131,072 B

    hipMemsetAsync(d_out, 0, sizeof(float), stream);
    hipMemsetAsync(ws + 8388608, 0, 3 * 131072, stream);       // zero the atomic targets
    cast_reorder_kernel<<<4096, 256, 0, stream>>>(feat, contrast);
    supcon_main_kernel<<<1024, 256, 0, stream>>>(contrast, labels, rsum_ws, ps_ws, sd_ws);
    finalize_kernel<<<128, 256, 0, stream>>>(labels, rsum_ws, ps_ws, sd_ws, out);
}